// Round 10
// baseline (24.480 us; speedup 1.0000x reference)
//
#include <hip/hip_runtime.h>
#include <hip/hip_bf16.h>

// x: (N=8, C=512, T=32, H=14, W=14) fp32 = 131072 rows x 196 floats.
// Single fused halo kernel, dual-stream ILP variant.
// Block = (n, 128 owned channels, 1 timestep): 8*4*32 = 1024 blocks, 256 thr,
//   4 blocks/CU (launch_bounds(256,4) -> VGPR<=128).
// Rows needed: 128 + 4 halo = 132 (channels c0-2 .. c0+129, zero-pad OOB).
// 64 quads (4 threads each): quad k GAP-reduces rows k and k+64 with
//   INTERLEAVED float4 load streams (2x bytes in flight vs R9), then quads
//   0..3 do tail rows 128..131. Results -> LDS[132].
// Phase 2: threads 0..127 compute 5-tap conv + sigmoid from LDS, write out.

#define F4_PER_ROW 49
#define OWN_CH 128
#define ROWS_TOT (OWN_CH + 4)   // 132

__device__ __forceinline__ float row_base_sum_single(
        const float* __restrict__ x, int n, int c, int t, int q, float4* tail) {
    // returns partial sum for quad lane q of row (n,c,t); caller handles OOB c.
    const int row = (n * 512 + c) * 32 + t;
    const float4* p = reinterpret_cast<const float4*>(x) +
                      (size_t)row * F4_PER_ROW + q;
    float4 a0 = p[0];
    float4 a1 = p[4];
    #pragma unroll
    for (int i = 2; i < 12; i += 2) {
        float4 u = p[4 * i];
        float4 v = p[4 * (i + 1)];
        a0.x += u.x; a0.y += u.y; a0.z += u.z; a0.w += u.w;
        a1.x += v.x; a1.y += v.y; a1.z += v.z; a1.w += v.w;
    }
    float s = ((a0.x + a1.x) + (a0.y + a1.y)) + ((a0.z + a1.z) + (a0.w + a1.w));
    if (q == 0) {
        float4 u = p[48];
        s += (u.x + u.y) + (u.z + u.w);
    }
    (void)tail;
    return s;
}

__global__ __launch_bounds__(256, 4) void fused_halo2_kernel(
        const float* __restrict__ x,
        const float* __restrict__ w,
        float* __restrict__ out) {
    const int bid = blockIdx.x;
    const int n   = bid >> 7;           // 128 blocks per image
    const int cb  = (bid >> 5) & 3;     // channel tile (128 ch)
    const int t0  = bid & 31;           // timestep
    const int c0  = cb * OWN_CH;

    const int tid = threadIdx.x;
    const int k   = tid >> 2;           // quad id 0..63
    const int q   = tid & 3;

    __shared__ float gs[ROWS_TOT];

    // ---- Phase 1: dual-stream GAP. Rows rA=k, rB=k+64 (c = c0-2+r). ----
    const int cA = c0 - 2 + k;
    const int cB = c0 - 2 + k + 64;
    const bool vA = (cA >= 0) && (cA < 512);
    const bool vB = (cB >= 0) && (cB < 512);
    // OOB rows read row 0 harmlessly (x is valid there), result masked to 0.
    const int rowA = (n * 512 + (vA ? cA : 0)) * 32 + t0;
    const int rowB = (n * 512 + (vB ? cB : 0)) * 32 + t0;
    const float4* pA = reinterpret_cast<const float4*>(x) +
                       (size_t)rowA * F4_PER_ROW + q;
    const float4* pB = reinterpret_cast<const float4*>(x) +
                       (size_t)rowB * F4_PER_ROW + q;

    float4 a0 = pA[0];
    float4 b0 = pB[0];
    float4 a1 = pA[4];
    float4 b1 = pB[4];
    #pragma unroll
    for (int i = 2; i < 12; i += 2) {
        float4 uA = pA[4 * i];
        float4 uB = pB[4 * i];
        float4 vA4 = pA[4 * (i + 1)];
        float4 vB4 = pB[4 * (i + 1)];
        a0.x += uA.x; a0.y += uA.y; a0.z += uA.z; a0.w += uA.w;
        b0.x += uB.x; b0.y += uB.y; b0.z += uB.z; b0.w += uB.w;
        a1.x += vA4.x; a1.y += vA4.y; a1.z += vA4.z; a1.w += vA4.w;
        b1.x += vB4.x; b1.y += vB4.y; b1.z += vB4.z; b1.w += vB4.w;
    }
    float sA = ((a0.x + a1.x) + (a0.y + a1.y)) + ((a0.z + a1.z) + (a0.w + a1.w));
    float sB = ((b0.x + b1.x) + (b0.y + b1.y)) + ((b0.z + b1.z) + (b0.w + b1.w));
    if (q == 0) {
        float4 uA = pA[48];
        float4 uB = pB[48];
        sA += (uA.x + uA.y) + (uA.z + uA.w);
        sB += (uB.x + uB.y) + (uB.z + uB.w);
    }
    sA += __shfl_xor(sA, 1, 64);
    sA += __shfl_xor(sA, 2, 64);
    sB += __shfl_xor(sB, 1, 64);
    sB += __shfl_xor(sB, 2, 64);
    if (q == 0) {
        gs[k]      = vA ? sA * (1.0f / 196.0f) : 0.0f;
        gs[k + 64] = vB ? sB * (1.0f / 196.0f) : 0.0f;
    }

    // ---- Tail rows 128..131 (quads 0..3) ----
    if (k < 4) {
        const int r  = 128 + k;
        const int c  = c0 - 2 + r;
        const bool v = (c >= 0) && (c < 512);
        float s = 0.0f;
        if (v) s = row_base_sum_single(x, n, c, t0, q, nullptr);
        s += __shfl_xor(s, 1, 64);
        s += __shfl_xor(s, 2, 64);
        if (q == 0) gs[r] = v ? s * (1.0f / 196.0f) : 0.0f;
    }
    __syncthreads();

    // ---- Phase 2: 128 outputs, one per thread ----
    if (tid < OWN_CH) {
        const float acc =
            w[0] * gs[tid + 0] +
            w[1] * gs[tid + 1] +
            w[2] * gs[tid + 2] +
            w[3] * gs[tid + 3] +
            w[4] * gs[tid + 4];
        out[(n * 512 + c0 + tid) * 32 + t0] = 1.0f / (1.0f + __expf(-acc));
    }
}

extern "C" void kernel_launch(void* const* d_in, const int* in_sizes, int n_in,
                              void* d_out, int out_size, void* d_ws, size_t ws_size,
                              hipStream_t stream) {
    const float* x = (const float*)d_in[0];   // 8*512*32*14*14
    const float* w = (const float*)d_in[1];   // 5
    float* out = (float*)d_out;               // 8*512*32

    fused_halo2_kernel<<<1024, 256, 0, stream>>>(x, w, out);
}

// Round 11
// 23.843 us; speedup vs baseline: 1.0267x; 1.0267x over previous
//
#include <hip/hip_runtime.h>
#include <hip/hip_bf16.h>

// x: (N=8, C=512, T=32, H=14, W=14) fp32 = 131072 rows x 196 floats.
// Single fused halo kernel, minimal-halo tiling.
// Block = (n, 64 owned channels, 1 timestep): 8*8*32 = 2048 blocks (8/CU),
//   256 threads. Rows needed = 64 + 4 halo = 68 (channels c0-2 .. c0+65,
//   zero-pad OOB). Halo overhead 6.25% (vs 12.5% in R9).
// Phase 1: quad scheme (4 threads/row, strided float4, 2x shfl_xor) for rows
//   0..63 (quad k -> channel c0-2+k), then quads 0..3 do tail rows 64..67.
// Phase 2: threads 0..63 compute the 5-tap channel conv + sigmoid from LDS.

#define F4_PER_ROW 49
#define OWN 64
#define ROWS_TOT (OWN + 4)   // 68

__device__ __forceinline__ float quad_row_sum(
        const float* __restrict__ x, int row, int q) {
    const float4* p = reinterpret_cast<const float4*>(x) +
                      (size_t)row * F4_PER_ROW + q;
    float4 a0 = p[0];
    float4 a1 = p[4];
    #pragma unroll
    for (int i = 2; i < 12; i += 2) {
        float4 u = p[4 * i];
        float4 v = p[4 * (i + 1)];
        a0.x += u.x; a0.y += u.y; a0.z += u.z; a0.w += u.w;
        a1.x += v.x; a1.y += v.y; a1.z += v.z; a1.w += v.w;
    }
    float s = ((a0.x + a1.x) + (a0.y + a1.y)) + ((a0.z + a1.z) + (a0.w + a1.w));
    if (q == 0) {
        float4 u = p[48];
        s += (u.x + u.y) + (u.z + u.w);
    }
    return s;
}

__global__ __launch_bounds__(256, 8) void fused_halo64_kernel(
        const float* __restrict__ x,
        const float* __restrict__ w,
        float* __restrict__ out) {
    const int bid = blockIdx.x;
    const int t0  = bid & 31;          // timestep
    const int cb  = (bid >> 5) & 7;    // channel tile
    const int n   = bid >> 8;          // image
    const int c0  = cb * OWN;

    const int tid = threadIdx.x;
    const int k   = tid >> 2;          // quad id 0..63
    const int q   = tid & 3;

    __shared__ float gs[ROWS_TOT];

    // ---- Phase 1 main: row index k -> channel c0-2+k ----
    {
        const int c = c0 - 2 + k;
        const bool v = (c >= 0) && (c < 512);
        float s = 0.0f;
        if (v) s = quad_row_sum(x, (n * 512 + c) * 32 + t0, q);
        s += __shfl_xor(s, 1, 64);
        s += __shfl_xor(s, 2, 64);
        if (q == 0) gs[k] = v ? s * (1.0f / 196.0f) : 0.0f;
    }

    // ---- Phase 1 tail: rows 64..67 -> channels c0+62..c0+65 (quads 0..3) ----
    if (k < 4) {
        const int c = c0 + 62 + k;
        const bool v = (c < 512);
        float s = 0.0f;
        if (v) s = quad_row_sum(x, (n * 512 + c) * 32 + t0, q);
        s += __shfl_xor(s, 1, 64);
        s += __shfl_xor(s, 2, 64);
        if (q == 0) gs[64 + k] = v ? s * (1.0f / 196.0f) : 0.0f;
    }
    __syncthreads();

    // ---- Phase 2: 64 outputs, one per thread ----
    if (tid < OWN) {
        const float acc =
            w[0] * gs[tid + 0] +
            w[1] * gs[tid + 1] +
            w[2] * gs[tid + 2] +
            w[3] * gs[tid + 3] +
            w[4] * gs[tid + 4];
        out[(n * 512 + c0 + tid) * 32 + t0] = 1.0f / (1.0f + __expf(-acc));
    }
}

extern "C" void kernel_launch(void* const* d_in, const int* in_sizes, int n_in,
                              void* d_out, int out_size, void* d_ws, size_t ws_size,
                              hipStream_t stream) {
    const float* x = (const float*)d_in[0];   // 8*512*32*14*14
    const float* w = (const float*)d_in[1];   // 5
    float* out = (float*)d_out;               // 8*512*32

    fused_halo64_kernel<<<2048, 256, 0, stream>>>(x, w, out);
}